// Round 8
// baseline (49855.154 us; speedup 1.0000x reference)
//
#include <hip/hip_runtime.h>

#define GRAV 9.80665f
// Single-wave sync: drain LDS ops; no s_barrier, no vmcnt drain.
#define WAVE_SYNC() do { \
    asm volatile("s_waitcnt lgkmcnt(0)" ::: "memory"); \
    __builtin_amdgcn_sched_barrier(0); \
  } while(0)

#define LDP 28   // padded row stride for Pm/Eb (112 B, 16-aligned)

__device__ __forceinline__ float sel3(int r, float a0, float a1, float a2){
  float x = (r==1)? a1 : a0;
  return (r>=2)? a2 : x;
}
__device__ __forceinline__ float RL(float v, int k){
  return __int_as_float(__builtin_amdgcn_readlane(__float_as_int(v), k));
}
__device__ __forceinline__ float pick9(int k, const float* X){
  float s=X[0];
  s=(k==1)?X[1]:s; s=(k==2)?X[2]:s; s=(k==3)?X[3]:s; s=(k==4)?X[4]:s;
  s=(k==5)?X[5]:s; s=(k==6)?X[6]:s; s=(k==7)?X[7]:s; s=(k==8)?X[8]:s;
  return s;
}

__device__ __forceinline__ void mm33(float* __restrict__ O, const float* A, const float* B){
#pragma unroll
  for(int r=0;r<3;++r){
#pragma unroll
    for(int c=0;c<3;++c){
      O[r*3+c] = A[r*3+0]*B[0*3+c] + A[r*3+1]*B[1*3+c] + A[r*3+2]*B[2*3+c];
    }
  }
}

__device__ __forceinline__ void rot_from_t2(float t_, float p0, float p1, float p2, float* R){
  float c_, k1_, k2_;
  if (t_ < 1e-4f){
    c_  = 1.f - t_*(0.5f - t_*((1.f/24.f) - t_*(1.f/720.f)));
    k2_ = 1.f - t_*((1.f/6.f) - t_*((1.f/120.f) - t_*(1.f/5040.f)));
    k1_ = 0.5f - t_*((1.f/24.f) - t_*(1.f/720.f));
  } else {
    float a = sqrtf(t_);
    c_ = __cosf(a);
    float s = __sinf(a);
    k2_ = s/a;
    k1_ = (1.f - c_)/t_;
  }
  R[0]=c_+k1_*p0*p0;      R[1]=k1_*p0*p1-k2_*p2;  R[2]=k1_*p0*p2+k2_*p1;
  R[3]=k1_*p0*p1+k2_*p2;  R[4]=c_+k1_*p1*p1;      R[5]=k1_*p1*p2-k2_*p0;
  R[6]=k1_*p0*p2-k2_*p1;  R[7]=k1_*p1*p2+k2_*p0;  R[8]=c_+k1_*p2*p2;
}

__device__ __forceinline__ void normalize_rot9(float* X){
#pragma unroll 1
  for(int it=0; it<8; ++it){
    float Y[9], Z[9];
#pragma unroll
    for(int r=0;r<3;++r)
#pragma unroll
      for(int c=0;c<3;++c)
        Y[r*3+c] = X[r*3+0]*X[c*3+0] + X[r*3+1]*X[c*3+1] + X[r*3+2]*X[c*3+2];
#pragma unroll
    for(int r=0;r<3;++r)
#pragma unroll
      for(int c=0;c<3;++c)
        Z[r*3+c] = Y[r*3+0]*X[0*3+c] + Y[r*3+1]*X[1*3+c] + Y[r*3+2]*X[2*3+c];
#pragma unroll
    for(int e=0;e<9;++e) X[e] = 1.5f*X[e] - 0.5f*Z[e];
  }
}

__device__ __forceinline__ float pick_state(int l,
    const float* Rt, const float* vv, const float* pp,
    const float* bw, const float* ba, const float* Rc, const float* tc){
  float s = Rt[0];
  s=(l==1)?Rt[1]:s;  s=(l==2)?Rt[2]:s;  s=(l==3)?Rt[3]:s;  s=(l==4)?Rt[4]:s;
  s=(l==5)?Rt[5]:s;  s=(l==6)?Rt[6]:s;  s=(l==7)?Rt[7]:s;  s=(l==8)?Rt[8]:s;
  s=(l==9)?vv[0]:s;  s=(l==10)?vv[1]:s; s=(l==11)?vv[2]:s;
  s=(l==12)?pp[0]:s; s=(l==13)?pp[1]:s; s=(l==14)?pp[2]:s;
  s=(l==15)?bw[0]:s; s=(l==16)?bw[1]:s; s=(l==17)?bw[2]:s;
  s=(l==18)?ba[0]:s; s=(l==19)?ba[1]:s; s=(l==20)?ba[2]:s;
  s=(l==21)?Rc[0]:s; s=(l==22)?Rc[1]:s; s=(l==23)?Rc[2]:s;
  s=(l==24)?Rc[3]:s; s=(l==25)?Rc[4]:s; s=(l==26)?Rc[5]:s;
  s=(l==27)?Rc[6]:s; s=(l==28)?Rc[7]:s; s=(l==29)?Rc[8]:s;
  s=(l==30)?tc[0]:s; s=(l==31)?tc[1]:s; s=(l==32)?tc[2]:s;
  return s;
}

__global__ __launch_bounds__(64,1)
void iekf_scan_kernel(const float* __restrict__ t,
                      const float* __restrict__ u,
                      const float* __restrict__ mcov,
                      const float* __restrict__ v_mes,
                      const float* __restrict__ ang0,
                      float* __restrict__ out, int N)
{
  const int l = threadIdx.x;
  __shared__ __align__(16) float Pm[21*LDP];  // exactly-symmetric P (rows contiguous)
  __shared__ __align__(16) float Eb[21*LDP];  // E = Phi @ M

  // ---- init covariance ----
  for (int e=l; e<21*LDP; e+=64){
    int r=e/LDP, c=e-(e/LDP)*LDP;
    float vI=0.f;
    if (r==c){
      if (r<2) vI=0.001f;
      else if (r==3||r==4) vI=0.1f;
      else if (r>=9&&r<12) vI=0.006f;
      else if (r>=12&&r<15) vI=0.004f;
      else if (r>=15&&r<18) vI=1e-6f;
      else if (r>=18&&r<21) vI=0.005f;
    }
    Pm[e]=vI;
  }

  // ---- per-lane output mapping ----
  int ostr=0; float* op = out;
  {
    int obase=0, ooff=0;
    if (l<9)       {obase=0;    ostr=9; ooff=l;}
    else if (l<12) {obase=9*N;  ostr=3; ooff=l-9;}
    else if (l<15) {obase=12*N; ostr=3; ooff=l-12;}
    else if (l<18) {obase=15*N; ostr=3; ooff=l-15;}
    else if (l<21) {obase=18*N; ostr=3; ooff=l-18;}
    else if (l<30) {obase=21*N; ostr=9; ooff=l-21;}
    else           {obase=30*N; ostr=3; ooff=l-30;}
    op = out + obase + ooff;
  }

  const int g21 = l/21;        // group 0..2 (3 for lane 63, masked out)
  const int c21 = l - g21*21;  // 0..20
  const int cw  = 9 + 4*g21;
  int l1 = l+21; if (l1>=63) l1-=63;
  int l2 = l+42; if (l2>=63) l2-=63;
  static const int cols[12] = {3,4,5, 9,10,11, 15,16,17, 18,19,20};

  // ---- initial state (uniform); lane element in myval; row-0 outputs ----
  float myval = 0.f;
  {
    float Rt0[9], vv0[3], pp0[3], bwa[3], baa[3], Rc0[9], tca[3];
    float rl = ang0[0], pt = ang0[1], yw = ang0[2];
    float cr=cosf(rl), sr=sinf(rl), cp=cosf(pt), sp=sinf(pt), cy=cosf(yw), sy=sinf(yw);
    Rt0[0]=cy*cp; Rt0[1]=cy*sp*sr - sy*cr; Rt0[2]=cy*sp*cr + sy*sr;
    Rt0[3]=sy*cp; Rt0[4]=sy*sp*sr + cy*cr; Rt0[5]=sy*sp*cr - cy*sr;
    Rt0[6]=-sp;   Rt0[7]=cp*sr;            Rt0[8]=cp*cr;
    vv0[0]=v_mes[0]; vv0[1]=v_mes[1]; vv0[2]=v_mes[2];
#pragma unroll
    for(int k=0;k<3;++k){ pp0[k]=0.f; bwa[k]=0.f; baa[k]=0.f; tca[k]=0.f; }
    Rc0[0]=1.f;Rc0[1]=0.f;Rc0[2]=0.f;Rc0[3]=0.f;Rc0[4]=1.f;Rc0[5]=0.f;Rc0[6]=0.f;Rc0[7]=0.f;Rc0[8]=1.f;
    float sv = pick_state(l, Rt0, vv0, pp0, bwa, baa, Rc0, tca);
    if (l<33){ op[0] = sv; myval = sv; }
  }
  WAVE_SYNC();   // Pm init visible

  // ---- prefetch for i=1 ----
  float tA = t[0], tB = t[1];
  float cu[6];
#pragma unroll
  for(int k=0;k<6;++k) cu[k]=u[6+k];
  float cm0=mcov[2], cm1=mcov[3];

  int nx100=100, nx1000=1000;

#pragma unroll 1
  for (int i=1; i<N; ++i){
    float dt = tB - tA;
    float u0=cu[0], u1=cu[1], u2=cu[2], u3=cu[3], u4=cu[4], u5=cu[5];
    float crm0=cm0, crm1=cm1;
    if (i+1 < N){
      tA = tB; tB = t[i+1];
#pragma unroll
      for(int k=0;k<6;++k) cu[k]=u[(i+1)*6+k];
      cm0 = mcov[(i+1)*2]; cm1 = mcov[(i+1)*2+1];
    }

    // ---- state broadcast via readlane (no LDS) ----
    float Rt[9];
#pragma unroll
    for(int k=0;k<9;++k) Rt[k] = RL(myval, k);
    float vv0s=RL(myval,9),  vv1s=RL(myval,10), vv2s=RL(myval,11);
    float pp0s=RL(myval,12), pp1s=RL(myval,13), pp2s=RL(myval,14);
    float bw0=RL(myval,15),  bw1=RL(myval,16),  bw2=RL(myval,17);
    float ba0=RL(myval,18),  ba1=RL(myval,19),  ba2=RL(myval,20);
    float Rc[9];
#pragma unroll
    for(int k=0;k<9;++k) Rc[k] = RL(myval, 21+k);
    float tc0=RL(myval,30), tc1=RL(myval,31), tc2=RL(myval,32);

    float dt2=dt*dt, gdt=GRAV*dt, hdt=0.5f*dt, hdt2=0.5f*dt*dt;
    float hgdt2 = 0.5f*gdt*dt;
    float g6d   = gdt*dt2*(1.0f/6.0f);

    // ---- propagation chain (uniform) ----
    float w0=u0-bw0, w1=u1-bw1, w2=u2-bw2;
    float aa0=u3-ba0, aa1=u4-ba1, aa2=u5-ba2;
    float acc0 = Rt[0]*aa0+Rt[1]*aa1+Rt[2]*aa2;
    float acc1 = Rt[3]*aa0+Rt[4]*aa1+Rt[5]*aa2;
    float acc2 = Rt[6]*aa0+Rt[7]*aa1+Rt[8]*aa2 - GRAV;
    float vn0=vv0s+acc0*dt, vn1=vv1s+acc1*dt, vn2=vv2s+acc2*dt;
    float pn0=pp0s+vv0s*dt+acc0*hdt2;
    float pn1=pp1s+vv1s*dt+acc1*hdt2;
    float pn2=pp2s+vv2s*dt+acc2*hdt2;
    float ph0=w0*dt, ph1=w1*dt, ph2=w2*dt;
    float dRs[9]; rot_from_t2(ph0*ph0+ph1*ph1+ph2*ph2, ph0,ph1,ph2, dRs);
    float Rn[9]; mm33(Rn, Rt, dRs);

    // ---- Phi rows for MY group ----
    float RtG[3], RtA[3], RtB[3];
#pragma unroll
    for(int k=0;k<3;++k){
      float r0=Rt[k], r3=Rt[3+k], r6=Rt[6+k];
      RtG[k] = sel3(g21, r0, r3, r6);
      RtA[k] = sel3(g21, r3, r6, r0);
      RtB[k] = sel3(g21, r6, r0, r3);
    }
    float vAs = sel3(g21, vv2s, vv0s, vv1s), vBs = sel3(g21, vv1s, vv2s, vv0s);
    float pAs = sel3(g21, pp2s, pp0s, pp1s), pBs = sel3(g21, pp1s, pp2s, pp0s);
    float Bs0,Bs1,Bs2, Cs0,Cs1,Cs2, Ds0,Ds1,Ds2;
    {
      float bs[3], cs[3], ds[3];
#pragma unroll
      for(int k=0;k<3;++k){
        bs[k] = -dt*RtG[k];
        float craw = dt*(vAs*RtA[k] - vBs*RtB[k]);
        float selC = sel3(g21, -RtA[k], RtB[k], 0.f);
        cs[k] = craw + hgdt2*selC;
        float draw = dt*(pAs*RtA[k] - pBs*RtB[k]);
        ds[k] = draw + hdt*craw + g6d*selC;
      }
      Bs0=bs[0];Bs1=bs[1];Bs2=bs[2];
      Cs0=cs[0];Cs1=cs[1];Cs2=cs[2];
      Ds0=ds[0];Ds1=ds[1];Ds2=ds[2];
    }

    float q0d=0.001f*dt2, q1d=0.01f*dt2;
    float q69=6e-9f*dt2, q24=2e-4f*dt2, q19=1e-9f*dt2;

    // ===== stage E: read ROW c of exactly-symmetric P (vectorized) =====
    if (l<63){
      int c = c21;
      const float4* Pr4 = (const float4*)(Pm + c*LDP);
      float4 a0=Pr4[0], a1=Pr4[1], a2=Pr4[2], a3=Pr4[3], a4=Pr4[4];
      float m20 = Pm[c*LDP + 20];

      bool cl3 = (c<3);
      bool c36 = (c>=3 && c<6);
      int csel = c36 ? (c-3) : (cl3 ? c : 0);
      float Rtc0 = sel3(csel, Rt[0], Rt[3], Rt[6]);
      float Rtc1 = sel3(csel, Rt[1], Rt[4], Rt[7]);
      float Rtc2 = sel3(csel, Rt[2], Rt[5], Rt[8]);
      float dot0 = Rt[0]*Rtc0 + Rt[1]*Rtc1 + Rt[2]*Rtc2;
      float dot1 = Rt[3]*Rtc0 + Rt[4]*Rtc1 + Rt[5]*Rtc2;
      float dotg = RtG[0]*Rtc0 + RtG[1]*Rtc1 + RtG[2]*Rtc2;

      float m0  = a0.x + (cl3 ? q0d*dot0 : 0.f);
      float m1  = a0.y + (cl3 ? q0d*dot1 : 0.f);
      float mr  = sel3(g21, a0.x, a0.y, a0.z) + (cl3 ? q0d*dotg : 0.f);
      float m3r = sel3(g21, a0.w, a1.x, a1.y) + (c36 ? q1d*dotg : 0.f);
      float m6r = sel3(g21, a1.z, a1.w, a2.x);
      float m9  = a2.y + ((c==9) ? q69 : 0.f);
      float m10 = a2.z + ((c==10)? q69 : 0.f);
      float m11 = a2.w + ((c==11)? q69 : 0.f);
      float m12 = a3.x + ((c==12)? q24 : 0.f);
      float m13 = a3.y + ((c==13)? q24 : 0.f);
      float m14 = a3.z + ((c==14)? q24 : 0.f);

      float Ar = (g21==0)? gdt*m1 : (g21==1)? -gdt*m0 : 0.f;
      float bterm = Bs0*m12+Bs1*m13+Bs2*m14;
      float e0 = mr + Bs0*m9+Bs1*m10+Bs2*m11;
      float e1 = m3r + Ar + Cs0*m9+Cs1*m10+Cs2*m11 + bterm;
      float e2 = m6r + hdt*Ar + dt*m3r + Ds0*m9+Ds1*m10+Ds2*m11 + hdt*bterm;
      Eb[g21*LDP+c]=e0; Eb[(3+g21)*LDP+c]=e1; Eb[(6+g21)*LDP+c]=e2;

      // copy rows cw..cw+3 (elements cw..cw+3 of row c) + diag q
      float mc0 = sel3(g21, a2.y, a3.y, a4.y);   // elem 9 /13/17
      float mc1 = sel3(g21, a2.z, a3.z, a4.z);   // elem 10/14/18
      float mc2 = sel3(g21, a2.w, a3.w, a4.w);   // elem 11/15/19
      float mc3 = sel3(g21, a3.x, a4.x, m20);    // elem 12/16/20
      float qd0 = sel3(g21, q69, q24, q19);
      float qd1 = sel3(g21, q69, q24, q19);
      float qd2 = sel3(g21, q69, q19, q19);
      float qd3 = sel3(g21, q24, q19, q19);
      Eb[(cw+0)*LDP+c] = mc0 + ((cw+0==c)? qd0 : 0.f);
      Eb[(cw+1)*LDP+c] = mc1 + ((cw+1==c)? qd1 : 0.f);
      Eb[(cw+2)*LDP+c] = mc2 + ((cw+2==c)? qd2 : 0.f);
      Eb[(cw+3)*LDP+c] = mc3 + ((cw+3==c)? qd3 : 0.f);
    }

    // ---- overlap zone (independent of Eb): H, vi, rr ----
    float H0[12], H1[12];
    float rr0, rr1;
    {
      float Rb1 = Rn[0]*Rc[1]+Rn[1]*Rc[4]+Rn[2]*Rc[7];
      float Rb4 = Rn[3]*Rc[1]+Rn[4]*Rc[4]+Rn[5]*Rc[7];
      float Rb7 = Rn[6]*Rc[1]+Rn[7]*Rc[4]+Rn[8]*Rc[7];
      float Rb2 = Rn[0]*Rc[2]+Rn[1]*Rc[5]+Rn[2]*Rc[8];
      float Rb5 = Rn[3]*Rc[2]+Rn[4]*Rc[5]+Rn[5]*Rc[8];
      float Rb8 = Rn[6]*Rc[2]+Rn[7]*Rc[5]+Rn[8]*Rc[8];
      float vi0 = Rn[0]*vn0+Rn[3]*vn1+Rn[6]*vn2;
      float vi1 = Rn[1]*vn0+Rn[4]*vn1+Rn[7]*vn2;
      float vi2 = Rn[2]*vn0+Rn[5]*vn1+Rn[8]*vn2;
      float vb1 = Rc[1]*vi0+Rc[4]*vi1+Rc[7]*vi2 + (tc2*w0 - tc0*w2);
      float vb2 = Rc[2]*vi0+Rc[5]*vi1+Rc[8]*vi2 + (tc0*w1 - tc1*w0);
      rr0 = -vb1; rr1 = -vb2;
      H0[0]=Rb1; H0[1]=Rb4; H0[2]=Rb7;
      H1[0]=Rb2; H1[1]=Rb5; H1[2]=Rb8;
      H0[3]=tc2;  H0[4]=0.f;  H0[5]=-tc0;
      H1[3]=-tc1; H1[4]=tc0;  H1[5]=0.f;
      H0[6]=Rc[4]*vi2 - Rc[7]*vi1;  H0[7]=Rc[7]*vi0 - Rc[1]*vi2;  H0[8]=Rc[1]*vi1 - Rc[4]*vi0;
      H1[6]=Rc[5]*vi2 - Rc[8]*vi1;  H1[7]=Rc[8]*vi0 - Rc[2]*vi2;  H1[8]=Rc[2]*vi1 - Rc[5]*vi0;
      H0[9]=-w2; H0[10]=0.f; H0[11]=w0;
      H1[9]=w1;  H1[10]=-w0; H1[11]=0.f;
    }
    WAVE_SYNC();  // W0: Eb visible (drain overlapped by H block)

    // ===== stage Pn: row r of P_n in registers + HP partials =====
    float pnv[7];
#pragma unroll
    for(int k=0;k<7;++k) pnv[k]=0.f;
    float p0=0.f, p1=0.f;
    if (l<63){
      int r = c21;
      const float4* Er4 = (const float4*)(Eb + r*LDP);
      float4 a0=Er4[0], a1=Er4[1], a2=Er4[2], a3=Er4[3], a4=Er4[4];
      float e20 = Eb[r*LDP + 20];

      float e0a=a0.x, e1a=a0.y;
      float eg  = sel3(g21, a0.x, a0.y, a0.z);
      float e3g = sel3(g21, a0.w, a1.x, a1.y);
      float e6g = sel3(g21, a1.z, a1.w, a2.x);
      float e9=a2.y, e10=a2.z, e11=a2.w, e12=a3.x, e13=a3.y, e14=a3.z;

      float Ag = (g21==0)? gdt*e1a : (g21==1)? -gdt*e0a : 0.f;
      float bterm = Bs0*e12+Bs1*e13+Bs2*e14;
      pnv[0] = eg + Bs0*e9+Bs1*e10+Bs2*e11;
      pnv[1] = e3g + Ag + Cs0*e9+Cs1*e10+Cs2*e11 + bterm;
      pnv[2] = e6g + hdt*Ag + dt*e3g + Ds0*e9+Ds1*e10+Ds2*e11 + hdt*bterm;
      pnv[3] = sel3(g21, a2.y, a3.y, a4.y);
      pnv[4] = sel3(g21, a2.z, a3.z, a4.z);
      pnv[5] = sel3(g21, a2.w, a3.w, a4.w);
      pnv[6] = sel3(g21, a3.x, a4.x, e20);

      float c1a = sel3(g21, H0[0], H0[1], H0[2]);
      float c3a = sel3(g21, H0[3], 0.f,   H0[8]);
      float c4a = sel3(g21, H0[4], 0.f,   H0[9]);
      float c5a = sel3(g21, H0[5], H0[6], H0[10]);
      float c6a = sel3(g21, 0.f,   H0[7], H0[11]);
      float c1b = sel3(g21, H1[0], H1[1], H1[2]);
      float c3b = sel3(g21, H1[3], 0.f,   H1[8]);
      float c4b = sel3(g21, H1[4], 0.f,   H1[9]);
      float c5b = sel3(g21, H1[5], H1[6], H1[10]);
      float c6b = sel3(g21, 0.f,   H1[7], H1[11]);
      p0 = c1a*pnv[1] + c3a*pnv[3] + c4a*pnv[4] + c5a*pnv[5] + c6a*pnv[6];
      p1 = c1b*pnv[1] + c3b*pnv[3] + c4b*pnv[4] + c5b*pnv[5] + c6b*pnv[6];
    }
    // combine partials; every lane ends with HP[:,r], r=c21 (group-0 lanes canonical)
    float hpr0 = p0 + __shfl(p0, l1) + __shfl(p0, l2);
    float hpr1 = p1 + __shfl(p1, l1) + __shfl(p1, l2);

    // ---- Pu cross-term fetch: HP[:,j] via per-lane-source shfl (no barrier) ----
    float hpjx[7], hpjy[7];
#pragma unroll
    for (int s=0;s<7;++s){
      int j = (s<3)? (g21 + 3*s) : (cw + (s-3));
      hpjx[s] = __shfl(hpr0, j);   // lane j (group 0) is canonical
      hpjy[s] = __shfl(hpr1, j);
    }

    // ===== S/K/dx via readlane (no LDS) =====
    float hph00=0.f, hph01=0.f, hph10=0.f, hph11=0.f;
#pragma unroll
    for(int k=0;k<12;++k){
      float hp0 = RL(hpr0, cols[k]);
      float hp1 = RL(hpr1, cols[k]);
      hph00 += hp0*H0[k]; hph01 += hp0*H1[k];
      hph10 += hp1*H0[k]; hph11 += hp1*H1[k];
    }
    float s00 = hph00 + crm0, s01 = hph01, s10 = hph10, s11 = hph11 + crm1;
    float idet = 1.0f/(s00*s11 - s01*s10);
    float i00 =  s11*idet, i01 = -s01*idet, i10 = -s10*idet, i11 = s00*idet;
    float K0 = i00*hpr0 + i01*hpr1;
    float K1 = i10*hpr0 + i11*hpr1;
    float s01q = 0.5f*(s01 + s10);
    float dxval = K0*rr0 + K1*rr1;

    float dx0 = RL(dxval,0), dx1 = RL(dxval,1), dx2 = RL(dxval,2);
    float dx3 = RL(dxval,3), dx4 = RL(dxval,4), dx5 = RL(dxval,5);
    float dx6 = RL(dxval,6), dx7 = RL(dxval,7), dx8 = RL(dxval,8);
    float dx15 = RL(dxval,15), dx16 = RL(dxval,16), dx17 = RL(dxval,17);
    int src = (l>=30 && l<33)? (l-12) : ((l>=15 && l<21)? (l-6) : 0);
    float dxadd = __shfl(dxval, src);

    // ===== stage Pu: pair-ownership symmetric write =====
    // Pu[r][j] = Pn[r][j] - (K[r].HP[:,j] + K[j].HP[:,r]) + K[r] Ssym K[j]
    // owner (r<=j) writes BOTH Pm[r][j] and Pm[j][r] -> P exactly symmetric.
    if (l<63){
      int r = c21;
#pragma unroll
      for (int s=0;s<7;++s){
        int j = (s<3)? (g21 + 3*s) : (cw + (s-3));
        float kjx = i00*hpjx[s] + i01*hpjy[s];
        float kjy = i10*hpjx[s] + i11*hpjy[s];
        float cross = (K0*hpjx[s] + K1*hpjy[s]) + (kjx*hpr0 + kjy*hpr1);
        float quad  = (K0*kjx)*s00 + (K0*kjy + K1*kjx)*s01q + (K1*kjy)*s11;
        float val = pnv[s] - cross + quad;
        if (r <= j){
          Pm[r*LDP+j] = val;
          if (r < j) Pm[j*LDP+r] = val;
        }
      }
    }

    // ---- dR, Jm, Ec (uniform) ----
    float t2x = dx0*dx0+dx1*dx1+dx2*dx2;
    float cX,k1X,k2X,j1X;
    if (t2x < 1e-4f){
      cX  = 1.f - t2x*(0.5f - t2x*((1.f/24.f) - t2x*(1.f/720.f)));
      k2X = 1.f - t2x*((1.f/6.f) - t2x*((1.f/120.f) - t2x*(1.f/5040.f)));
      k1X = 0.5f - t2x*((1.f/24.f) - t2x*(1.f/720.f));
      j1X = (1.f/6.f) - t2x*((1.f/120.f) - t2x*(1.f/5040.f));
    } else {
      float a = sqrtf(t2x);
      cX = __cosf(a);
      float s = __sinf(a);
      k2X = s/a; k1X = (1.f-cX)/t2x; j1X = (1.f-k2X)/t2x;
    }
    float dR[9];
    dR[0]=cX+k1X*dx0*dx0;      dR[1]=k1X*dx0*dx1-k2X*dx2; dR[2]=k1X*dx0*dx2+k2X*dx1;
    dR[3]=k1X*dx0*dx1+k2X*dx2; dR[4]=cX+k1X*dx1*dx1;      dR[5]=k1X*dx1*dx2-k2X*dx0;
    dR[6]=k1X*dx0*dx2-k2X*dx1; dR[7]=k1X*dx1*dx2+k2X*dx0; dR[8]=cX+k1X*dx2*dx2;
    float Jm[9];
    Jm[0]=k2X+j1X*dx0*dx0;      Jm[1]=j1X*dx0*dx1-k1X*dx2; Jm[2]=j1X*dx0*dx2+k1X*dx1;
    Jm[3]=j1X*dx0*dx1+k1X*dx2;  Jm[4]=k2X+j1X*dx1*dx1;     Jm[5]=j1X*dx1*dx2-k1X*dx0;
    Jm[6]=j1X*dx0*dx2-k1X*dx1;  Jm[7]=j1X*dx1*dx2+k1X*dx0; Jm[8]=k2X+j1X*dx2*dx2;
    float Ec[9];
    rot_from_t2(dx15*dx15+dx16*dx16+dx17*dx17, dx15,dx16,dx17, Ec);

    // ===== per-lane state update =====
    float nv = 0.f;
    if (l<9){
      int ro=(l>=6)?2:((l>=3)?1:0); int co=l-3*ro;
      float d0=sel3(ro,dR[0],dR[3],dR[6]), d1=sel3(ro,dR[1],dR[4],dR[7]), d2=sel3(ro,dR[2],dR[5],dR[8]);
      float n0=sel3(co,Rn[0],Rn[1],Rn[2]), n1=sel3(co,Rn[3],Rn[4],Rn[5]), n2=sel3(co,Rn[6],Rn[7],Rn[8]);
      nv = d0*n0 + d1*n1 + d2*n2;
    } else if (l<15){
      int j=l-9; bool isv=(j<3); int ro = isv? j : (j-3);
      float x0 = isv? vn0:pn0, x1 = isv? vn1:pn1, x2 = isv? vn2:pn2;
      float y0 = isv? dx3:dx6, y1 = isv? dx4:dx7, y2 = isv? dx5:dx8;
      float d0=sel3(ro,dR[0],dR[3],dR[6]), d1=sel3(ro,dR[1],dR[4],dR[7]), d2=sel3(ro,dR[2],dR[5],dR[8]);
      float j0=sel3(ro,Jm[0],Jm[3],Jm[6]), j1m=sel3(ro,Jm[1],Jm[4],Jm[7]), j2m=sel3(ro,Jm[2],Jm[5],Jm[8]);
      nv = d0*x0 + d1*x1 + d2*x2 + j0*y0 + j1m*y1 + j2m*y2;
    } else if (l<21){
      float old = (l<18)? sel3(l-15,bw0,bw1,bw2) : sel3(l-18,ba0,ba1,ba2);
      nv = old + dxadd;
    } else if (l<30){
      int j=l-21; int ro=(j>=6)?2:((j>=3)?1:0); int co=j-3*ro;
      float e0=sel3(ro,Ec[0],Ec[3],Ec[6]), e1=sel3(ro,Ec[1],Ec[4],Ec[7]), e2=sel3(ro,Ec[2],Ec[5],Ec[8]);
      float r0=sel3(co,Rc[0],Rc[1],Rc[2]), r1=sel3(co,Rc[3],Rc[4],Rc[5]), r2=sel3(co,Rc[6],Rc[7],Rc[8]);
      nv = e0*r0 + e1*r1 + e2*r2;
    } else if (l<33){
      nv = sel3(l-30,tc0,tc1,tc2) + dxadd;
    }
    if (l<33) myval = nv;

    // ---- periodic renormalization (uniform branch; readlane-based, no sync) ----
    bool n100 = (i==nx100), n1000 = (i==nx1000);
    if (n100) nx100 += 100;
    if (n1000) nx1000 += 1000;
    if (n100 || n1000){
      if (n100){
        float X[9];
#pragma unroll
        for (int k=0;k<9;++k) X[k]=RL(myval,k);
        normalize_rot9(X);
        if (l<9) myval = pick9(l,X);
      }
      if (n1000){
        float Y[9];
#pragma unroll
        for (int k=0;k<9;++k) Y[k]=RL(myval,21+k);
        normalize_rot9(Y);
        if (l>=21 && l<30) myval = pick9(l-21,Y);
      }
    }

    if (l<33) op[i*ostr] = myval;

    WAVE_SYNC();  // W2: Pm writes visible for next iteration's stage E
  }
}

extern "C" void kernel_launch(void* const* d_in, const int* in_sizes, int n_in,
                              void* d_out, int out_size, void* d_ws, size_t ws_size,
                              hipStream_t stream) {
  (void)n_in; (void)out_size; (void)d_ws; (void)ws_size;
  const float* t     = (const float*)d_in[0];
  const float* u     = (const float*)d_in[1];
  const float* mcov  = (const float*)d_in[2];
  const float* v_mes = (const float*)d_in[3];
  const float* ang0  = (const float*)d_in[5];
  int N = in_sizes[0];
  iekf_scan_kernel<<<dim3(1), dim3(64), 0, stream>>>(t, u, mcov, v_mes, ang0, (float*)d_out, N);
}

// Round 9
// 44246.317 us; speedup vs baseline: 1.1268x; 1.1268x over previous
//
#include <hip/hip_runtime.h>

#define GRAV 9.80665f
// Single-wave sync: drain LDS ops; no s_barrier, no vmcnt drain.
#define WAVE_SYNC() do { \
    asm volatile("s_waitcnt lgkmcnt(0)" ::: "memory"); \
    __builtin_amdgcn_sched_barrier(0); \
  } while(0)

#define LDP 28   // padded row stride for Pm/Eb/PnS (112 B, 16-aligned)

__device__ __forceinline__ float sel3(int r, float a0, float a1, float a2){
  float x = (r==1)? a1 : a0;
  return (r>=2)? a2 : x;
}
__device__ __forceinline__ float RL(float v, int k){
  return __int_as_float(__builtin_amdgcn_readlane(__float_as_int(v), k));
}
__device__ __forceinline__ float pick9(int k, const float* X){
  float s=X[0];
  s=(k==1)?X[1]:s; s=(k==2)?X[2]:s; s=(k==3)?X[3]:s; s=(k==4)?X[4]:s;
  s=(k==5)?X[5]:s; s=(k==6)?X[6]:s; s=(k==7)?X[7]:s; s=(k==8)?X[8]:s;
  return s;
}

__device__ __forceinline__ void mm33(float* __restrict__ O, const float* A, const float* B){
#pragma unroll
  for(int r=0;r<3;++r){
#pragma unroll
    for(int c=0;c<3;++c){
      O[r*3+c] = A[r*3+0]*B[0*3+c] + A[r*3+1]*B[1*3+c] + A[r*3+2]*B[2*3+c];
    }
  }
}

__device__ __forceinline__ void rot_from_t2(float t_, float p0, float p1, float p2, float* R){
  float c_, k1_, k2_;
  if (t_ < 1e-4f){
    c_  = 1.f - t_*(0.5f - t_*((1.f/24.f) - t_*(1.f/720.f)));
    k2_ = 1.f - t_*((1.f/6.f) - t_*((1.f/120.f) - t_*(1.f/5040.f)));
    k1_ = 0.5f - t_*((1.f/24.f) - t_*(1.f/720.f));
  } else {
    float a = sqrtf(t_);
    c_ = __cosf(a);
    float s = __sinf(a);
    k2_ = s/a;
    k1_ = (1.f - c_)/t_;
  }
  R[0]=c_+k1_*p0*p0;      R[1]=k1_*p0*p1-k2_*p2;  R[2]=k1_*p0*p2+k2_*p1;
  R[3]=k1_*p0*p1+k2_*p2;  R[4]=c_+k1_*p1*p1;      R[5]=k1_*p1*p2-k2_*p0;
  R[6]=k1_*p0*p2-k2_*p1;  R[7]=k1_*p1*p2+k2_*p0;  R[8]=c_+k1_*p2*p2;
}

__device__ __forceinline__ void normalize_rot9(float* X){
#pragma unroll 1
  for(int it=0; it<8; ++it){
    float Y[9], Z[9];
#pragma unroll
    for(int r=0;r<3;++r)
#pragma unroll
      for(int c=0;c<3;++c)
        Y[r*3+c] = X[r*3+0]*X[c*3+0] + X[r*3+1]*X[c*3+1] + X[r*3+2]*X[c*3+2];
#pragma unroll
    for(int r=0;r<3;++r)
#pragma unroll
      for(int c=0;c<3;++c)
        Z[r*3+c] = Y[r*3+0]*X[0*3+c] + Y[r*3+1]*X[1*3+c] + Y[r*3+2]*X[2*3+c];
#pragma unroll
    for(int e=0;e<9;++e) X[e] = 1.5f*X[e] - 0.5f*Z[e];
  }
}

__device__ __forceinline__ float pick_state(int l,
    const float* Rt, const float* vv, const float* pp,
    const float* bw, const float* ba, const float* Rc, const float* tc){
  float s = Rt[0];
  s=(l==1)?Rt[1]:s;  s=(l==2)?Rt[2]:s;  s=(l==3)?Rt[3]:s;  s=(l==4)?Rt[4]:s;
  s=(l==5)?Rt[5]:s;  s=(l==6)?Rt[6]:s;  s=(l==7)?Rt[7]:s;  s=(l==8)?Rt[8]:s;
  s=(l==9)?vv[0]:s;  s=(l==10)?vv[1]:s; s=(l==11)?vv[2]:s;
  s=(l==12)?pp[0]:s; s=(l==13)?pp[1]:s; s=(l==14)?pp[2]:s;
  s=(l==15)?bw[0]:s; s=(l==16)?bw[1]:s; s=(l==17)?bw[2]:s;
  s=(l==18)?ba[0]:s; s=(l==19)?ba[1]:s; s=(l==20)?ba[2]:s;
  s=(l==21)?Rc[0]:s; s=(l==22)?Rc[1]:s; s=(l==23)?Rc[2]:s;
  s=(l==24)?Rc[3]:s; s=(l==25)?Rc[4]:s; s=(l==26)?Rc[5]:s;
  s=(l==27)?Rc[6]:s; s=(l==28)?Rc[7]:s; s=(l==29)?Rc[8]:s;
  s=(l==30)?tc[0]:s; s=(l==31)?tc[1]:s; s=(l==32)?tc[2]:s;
  return s;
}

// State LDS layout: [0..8]=Rot, [9..11]=v, [12..14]=p, [15..17]=b_om,
// [18..20]=b_ac, [21..29]=Rci, [30..32]=tci.
__global__ __launch_bounds__(64,1)
void iekf_scan_kernel(const float* __restrict__ t,
                      const float* __restrict__ u,
                      const float* __restrict__ mcov,
                      const float* __restrict__ v_mes,
                      const float* __restrict__ ang0,
                      float* __restrict__ out, int N)
{
  const int l = threadIdx.x;
  __shared__ __align__(16) float Pm[21*LDP];   // exactly-symmetric P
  __shared__ __align__(16) float Eb[21*LDP];   // E = Phi @ M
  __shared__ __align__(16) float PnS[21*LDP];  // P_n (for transpose reads)
  __shared__ float2 HPs2[21];
  __shared__ __align__(16) float stS[36];

  // ---- init covariance (+ zero padding) ----
  for (int e=l; e<21*LDP; e+=64){
    int r=e/LDP, c=e-(e/LDP)*LDP;
    float vI=0.f;
    if (r==c){
      if (r<2) vI=0.001f;
      else if (r==3||r==4) vI=0.1f;
      else if (r>=9&&r<12) vI=0.006f;
      else if (r>=12&&r<15) vI=0.004f;
      else if (r>=15&&r<18) vI=1e-6f;
      else if (r>=18&&r<21) vI=0.005f;
    }
    Pm[e]=vI;
  }

  // ---- per-lane output mapping ----
  int ostr=0; float* op = out;
  {
    int obase=0, ooff=0;
    if (l<9)       {obase=0;    ostr=9; ooff=l;}
    else if (l<12) {obase=9*N;  ostr=3; ooff=l-9;}
    else if (l<15) {obase=12*N; ostr=3; ooff=l-12;}
    else if (l<18) {obase=15*N; ostr=3; ooff=l-15;}
    else if (l<21) {obase=18*N; ostr=3; ooff=l-18;}
    else if (l<30) {obase=21*N; ostr=9; ooff=l-21;}
    else           {obase=30*N; ostr=3; ooff=l-30;}
    op = out + obase + ooff;
  }

  const int g21 = l/21;        // group 0..2 (3 for lane 63, masked out)
  const int c21 = l - g21*21;  // 0..20
  const int cw  = 9 + 4*g21;
  int l1 = l+21; if (l1>=63) l1-=63;
  int l2 = l+42; if (l2>=63) l2-=63;
  static const int cols[12] = {3,4,5, 9,10,11, 15,16,17, 18,19,20};

  // ---- initial state (uniform), publish to stS + row-0 outputs ----
  {
    float Rt0[9], vv0[3], pp0[3], bwa[3], baa[3], Rc0[9], tca[3];
    float rl = ang0[0], pt = ang0[1], yw = ang0[2];
    float cr=cosf(rl), sr=sinf(rl), cp=cosf(pt), sp=sinf(pt), cy=cosf(yw), sy=sinf(yw);
    Rt0[0]=cy*cp; Rt0[1]=cy*sp*sr - sy*cr; Rt0[2]=cy*sp*cr + sy*sr;
    Rt0[3]=sy*cp; Rt0[4]=sy*sp*sr + cy*cr; Rt0[5]=sy*sp*cr - cy*sr;
    Rt0[6]=-sp;   Rt0[7]=cp*sr;            Rt0[8]=cp*cr;
    vv0[0]=v_mes[0]; vv0[1]=v_mes[1]; vv0[2]=v_mes[2];
#pragma unroll
    for(int k=0;k<3;++k){ pp0[k]=0.f; bwa[k]=0.f; baa[k]=0.f; tca[k]=0.f; }
    Rc0[0]=1.f;Rc0[1]=0.f;Rc0[2]=0.f;Rc0[3]=0.f;Rc0[4]=1.f;Rc0[5]=0.f;Rc0[6]=0.f;Rc0[7]=0.f;Rc0[8]=1.f;
    float sv = pick_state(l, Rt0, vv0, pp0, bwa, baa, Rc0, tca);
    if (l<33){ op[0] = sv; stS[l] = sv; }
    if (l>=33 && l<36) stS[l] = 0.f;
  }
  WAVE_SYNC();

  // ---- prefetch for i=1 ----
  float tA = t[0], tB = t[1];
  float cu[6];
#pragma unroll
  for(int k=0;k<6;++k) cu[k]=u[6+k];
  float cm0=mcov[2], cm1=mcov[3];

  int nx100=100, nx1000=1000;

#pragma unroll 1
  for (int i=1; i<N; ++i){
    float dt = tB - tA;
    float u0=cu[0], u1=cu[1], u2=cu[2], u3=cu[3], u4=cu[4], u5=cu[5];
    float crm0=cm0, crm1=cm1;
    if (i+1 < N){
      tA = tB; tB = t[i+1];
#pragma unroll
      for(int k=0;k<6;++k) cu[k]=u[(i+1)*6+k];
      cm0 = mcov[(i+1)*2]; cm1 = mcov[(i+1)*2+1];
    }

    // ---- state from LDS (broadcast b128 reads) ----
    const float4* st4 = (const float4*)stS;
    float4 q0=st4[0], q1=st4[1], q2=st4[2], q3=st4[3], q4=st4[4], q5=st4[5], q6=st4[6], q7=st4[7], q8=st4[8];
    float Rt[9] = {q0.x,q0.y,q0.z,q0.w,q1.x,q1.y,q1.z,q1.w,q2.x};
    float vv0s=q2.y, vv1s=q2.z, vv2s=q2.w;
    float pp0s=q3.x, pp1s=q3.y, pp2s=q3.z;
    float bw0=q3.w, bw1=q4.x, bw2=q4.y;
    float ba0=q4.z, ba1=q4.w, ba2=q5.x;
    float Rc[9] = {q5.y,q5.z,q5.w,q6.x,q6.y,q6.z,q6.w,q7.x,q7.y};
    float tc0=q7.z, tc1=q7.w, tc2=q8.x;

    float dt2=dt*dt, gdt=GRAV*dt, hdt=0.5f*dt, hdt2=0.5f*dt*dt;
    float hgdt2 = 0.5f*gdt*dt;
    float g6d   = gdt*dt2*(1.0f/6.0f);

    // ---- Phi rows for MY group (needs only Rt, vv, pp, dt) ----
    float RtG[3], RtA[3], RtB[3];
#pragma unroll
    for(int k=0;k<3;++k){
      float r0=Rt[k], r3=Rt[3+k], r6=Rt[6+k];
      RtG[k] = sel3(g21, r0, r3, r6);
      RtA[k] = sel3(g21, r3, r6, r0);
      RtB[k] = sel3(g21, r6, r0, r3);
    }
    float vAs = sel3(g21, vv2s, vv0s, vv1s), vBs = sel3(g21, vv1s, vv2s, vv0s);
    float pAs = sel3(g21, pp2s, pp0s, pp1s), pBs = sel3(g21, pp1s, pp2s, pp0s);
    float Bs0,Bs1,Bs2, Cs0,Cs1,Cs2, Ds0,Ds1,Ds2;
    {
      float bs[3], cs[3], ds[3];
#pragma unroll
      for(int k=0;k<3;++k){
        bs[k] = -dt*RtG[k];
        float craw = dt*(vAs*RtA[k] - vBs*RtB[k]);
        float selC = sel3(g21, -RtA[k], RtB[k], 0.f);
        cs[k] = craw + hgdt2*selC;
        float draw = dt*(pAs*RtA[k] - pBs*RtB[k]);
        ds[k] = draw + hdt*craw + g6d*selC;
      }
      Bs0=bs[0];Bs1=bs[1];Bs2=bs[2];
      Cs0=cs[0];Cs1=cs[1];Cs2=cs[2];
      Ds0=ds[0];Ds1=ds[1];Ds2=ds[2];
    }

    float q0d=0.001f*dt2, q1d=0.01f*dt2;
    float q69=6e-9f*dt2, q24=2e-4f*dt2, q19=1e-9f*dt2;

    // ===== stage E FIRST (vectorized row reads of exactly-symmetric P) =====
    if (l<63){
      int c = c21;
      const float4* Pr4 = (const float4*)(Pm + c*LDP);
      float4 a0=Pr4[0], a1=Pr4[1], a2=Pr4[2], a3=Pr4[3], a4=Pr4[4];
      float m20 = Pm[c*LDP + 20];

      bool cl3 = (c<3);
      bool c36 = (c>=3 && c<6);
      int csel = c36 ? (c-3) : (cl3 ? c : 0);
      float Rtc0 = sel3(csel, Rt[0], Rt[3], Rt[6]);
      float Rtc1 = sel3(csel, Rt[1], Rt[4], Rt[7]);
      float Rtc2 = sel3(csel, Rt[2], Rt[5], Rt[8]);
      float dot0 = Rt[0]*Rtc0 + Rt[1]*Rtc1 + Rt[2]*Rtc2;
      float dot1 = Rt[3]*Rtc0 + Rt[4]*Rtc1 + Rt[5]*Rtc2;
      float dotg = RtG[0]*Rtc0 + RtG[1]*Rtc1 + RtG[2]*Rtc2;

      float m0  = a0.x + (cl3 ? q0d*dot0 : 0.f);
      float m1  = a0.y + (cl3 ? q0d*dot1 : 0.f);
      float mr  = sel3(g21, a0.x, a0.y, a0.z) + (cl3 ? q0d*dotg : 0.f);
      float m3r = sel3(g21, a0.w, a1.x, a1.y) + (c36 ? q1d*dotg : 0.f);
      float m6r = sel3(g21, a1.z, a1.w, a2.x);
      float m9  = a2.y + ((c==9) ? q69 : 0.f);
      float m10 = a2.z + ((c==10)? q69 : 0.f);
      float m11 = a2.w + ((c==11)? q69 : 0.f);
      float m12 = a3.x + ((c==12)? q24 : 0.f);
      float m13 = a3.y + ((c==13)? q24 : 0.f);
      float m14 = a3.z + ((c==14)? q24 : 0.f);

      float Ar = (g21==0)? gdt*m1 : (g21==1)? -gdt*m0 : 0.f;
      float bterm = Bs0*m12+Bs1*m13+Bs2*m14;
      float e0 = mr + Bs0*m9+Bs1*m10+Bs2*m11;
      float e1 = m3r + Ar + Cs0*m9+Cs1*m10+Cs2*m11 + bterm;
      float e2 = m6r + hdt*Ar + dt*m3r + Ds0*m9+Ds1*m10+Ds2*m11 + hdt*bterm;
      Eb[g21*LDP+c]=e0; Eb[(3+g21)*LDP+c]=e1; Eb[(6+g21)*LDP+c]=e2;

      float mc0 = sel3(g21, a2.y, a3.y, a4.y);   // elem 9 /13/17
      float mc1 = sel3(g21, a2.z, a3.z, a4.z);   // elem 10/14/18
      float mc2 = sel3(g21, a2.w, a3.w, a4.w);   // elem 11/15/19
      float mc3 = sel3(g21, a3.x, a4.x, m20);    // elem 12/16/20
      float qd0 = sel3(g21, q69, q24, q19);
      float qd1 = sel3(g21, q69, q24, q19);
      float qd2 = sel3(g21, q69, q19, q19);
      float qd3 = sel3(g21, q24, q19, q19);
      Eb[(cw+0)*LDP+c] = mc0 + ((cw+0==c)? qd0 : 0.f);
      Eb[(cw+1)*LDP+c] = mc1 + ((cw+1==c)? qd1 : 0.f);
      Eb[(cw+2)*LDP+c] = mc2 + ((cw+2==c)? qd2 : 0.f);
      Eb[(cw+3)*LDP+c] = mc3 + ((cw+3==c)? qd3 : 0.f);
    }

    // ---- propagation chain + H (independent of Eb -> covers W0 drain) ----
    float w0=u0-bw0, w1=u1-bw1, w2=u2-bw2;
    float aa0=u3-ba0, aa1=u4-ba1, aa2=u5-ba2;
    float acc0 = Rt[0]*aa0+Rt[1]*aa1+Rt[2]*aa2;
    float acc1 = Rt[3]*aa0+Rt[4]*aa1+Rt[5]*aa2;
    float acc2 = Rt[6]*aa0+Rt[7]*aa1+Rt[8]*aa2 - GRAV;
    float vn0=vv0s+acc0*dt, vn1=vv1s+acc1*dt, vn2=vv2s+acc2*dt;
    float pn0=pp0s+vv0s*dt+acc0*hdt2;
    float pn1=pp1s+vv1s*dt+acc1*hdt2;
    float pn2=pp2s+vv2s*dt+acc2*hdt2;
    float ph0=w0*dt, ph1=w1*dt, ph2=w2*dt;
    float dRs[9]; rot_from_t2(ph0*ph0+ph1*ph1+ph2*ph2, ph0,ph1,ph2, dRs);
    float Rn[9]; mm33(Rn, Rt, dRs);

    float H0[12], H1[12];
    float rr0, rr1;
    {
      float Rb1 = Rn[0]*Rc[1]+Rn[1]*Rc[4]+Rn[2]*Rc[7];
      float Rb4 = Rn[3]*Rc[1]+Rn[4]*Rc[4]+Rn[5]*Rc[7];
      float Rb7 = Rn[6]*Rc[1]+Rn[7]*Rc[4]+Rn[8]*Rc[7];
      float Rb2 = Rn[0]*Rc[2]+Rn[1]*Rc[5]+Rn[2]*Rc[8];
      float Rb5 = Rn[3]*Rc[2]+Rn[4]*Rc[5]+Rn[5]*Rc[8];
      float Rb8 = Rn[6]*Rc[2]+Rn[7]*Rc[5]+Rn[8]*Rc[8];
      float vi0 = Rn[0]*vn0+Rn[3]*vn1+Rn[6]*vn2;
      float vi1 = Rn[1]*vn0+Rn[4]*vn1+Rn[7]*vn2;
      float vi2 = Rn[2]*vn0+Rn[5]*vn1+Rn[8]*vn2;
      float vb1 = Rc[1]*vi0+Rc[4]*vi1+Rc[7]*vi2 + (tc2*w0 - tc0*w2);
      float vb2 = Rc[2]*vi0+Rc[5]*vi1+Rc[8]*vi2 + (tc0*w1 - tc1*w0);
      rr0 = -vb1; rr1 = -vb2;
      H0[0]=Rb1; H0[1]=Rb4; H0[2]=Rb7;
      H1[0]=Rb2; H1[1]=Rb5; H1[2]=Rb8;
      H0[3]=tc2;  H0[4]=0.f;  H0[5]=-tc0;
      H1[3]=-tc1; H1[4]=tc0;  H1[5]=0.f;
      H0[6]=Rc[4]*vi2 - Rc[7]*vi1;  H0[7]=Rc[7]*vi0 - Rc[1]*vi2;  H0[8]=Rc[1]*vi1 - Rc[4]*vi0;
      H1[6]=Rc[5]*vi2 - Rc[8]*vi1;  H1[7]=Rc[8]*vi0 - Rc[2]*vi2;  H1[8]=Rc[2]*vi1 - Rc[5]*vi0;
      H0[9]=-w2; H0[10]=0.f; H0[11]=w0;
      H1[9]=w1;  H1[10]=-w0; H1[11]=0.f;
    }
    WAVE_SYNC();  // W0: Eb visible (drain covered by the whole block above)

    // ===== stage Pn: vectorized Eb row read -> pnv + PnS + HP partials =====
    float pnv[7];
#pragma unroll
    for(int k=0;k<7;++k) pnv[k]=0.f;
    float p0=0.f, p1=0.f;
    if (l<63){
      int r = c21;
      const float4* Er4 = (const float4*)(Eb + r*LDP);
      float4 a0=Er4[0], a1=Er4[1], a2=Er4[2], a3=Er4[3], a4=Er4[4];
      float e20 = Eb[r*LDP + 20];

      float e0a=a0.x, e1a=a0.y;
      float eg  = sel3(g21, a0.x, a0.y, a0.z);
      float e3g = sel3(g21, a0.w, a1.x, a1.y);
      float e6g = sel3(g21, a1.z, a1.w, a2.x);
      float e9=a2.y, e10=a2.z, e11=a2.w, e12=a3.x, e13=a3.y, e14=a3.z;

      float Ag = (g21==0)? gdt*e1a : (g21==1)? -gdt*e0a : 0.f;
      float bterm = Bs0*e12+Bs1*e13+Bs2*e14;
      pnv[0] = eg + Bs0*e9+Bs1*e10+Bs2*e11;
      pnv[1] = e3g + Ag + Cs0*e9+Cs1*e10+Cs2*e11 + bterm;
      pnv[2] = e6g + hdt*Ag + dt*e3g + Ds0*e9+Ds1*e10+Ds2*e11 + hdt*bterm;
      pnv[3] = sel3(g21, a2.y, a3.y, a4.y);
      pnv[4] = sel3(g21, a2.z, a3.z, a4.z);
      pnv[5] = sel3(g21, a2.w, a3.w, a4.w);
      pnv[6] = sel3(g21, a3.x, a4.x, e20);

      PnS[r*LDP + g21]   = pnv[0];
      PnS[r*LDP + 3+g21] = pnv[1];
      PnS[r*LDP + 6+g21] = pnv[2];
      PnS[r*LDP + cw]    = pnv[3];
      PnS[r*LDP + cw+1]  = pnv[4];
      PnS[r*LDP + cw+2]  = pnv[5];
      PnS[r*LDP + cw+3]  = pnv[6];

      float c1a = sel3(g21, H0[0], H0[1], H0[2]);
      float c3a = sel3(g21, H0[3], 0.f,   H0[8]);
      float c4a = sel3(g21, H0[4], 0.f,   H0[9]);
      float c5a = sel3(g21, H0[5], H0[6], H0[10]);
      float c6a = sel3(g21, 0.f,   H0[7], H0[11]);
      float c1b = sel3(g21, H1[0], H1[1], H1[2]);
      float c3b = sel3(g21, H1[3], 0.f,   H1[8]);
      float c4b = sel3(g21, H1[4], 0.f,   H1[9]);
      float c5b = sel3(g21, H1[5], H1[6], H1[10]);
      float c6b = sel3(g21, 0.f,   H1[7], H1[11]);
      p0 = c1a*pnv[1] + c3a*pnv[3] + c4a*pnv[4] + c5a*pnv[5] + c6a*pnv[6];
      p1 = c1b*pnv[1] + c3b*pnv[3] + c4b*pnv[4] + c5b*pnv[5] + c6b*pnv[6];
    }
    float hpr0 = p0 + __shfl(p0, l1) + __shfl(p0, l2);
    float hpr1 = p1 + __shfl(p1, l1) + __shfl(p1, l2);
    if (l<21) HPs2[l] = make_float2(hpr0, hpr1);

    // ===== S/K/dx via readlane (covers W1 drain) =====
    float hph00=0.f, hph01=0.f, hph10=0.f, hph11=0.f;
#pragma unroll
    for(int k=0;k<12;++k){
      float hp0 = RL(hpr0, cols[k]);
      float hp1 = RL(hpr1, cols[k]);
      hph00 += hp0*H0[k]; hph01 += hp0*H1[k];
      hph10 += hp1*H0[k]; hph11 += hp1*H1[k];
    }
    float s00 = hph00 + crm0, s01 = hph01, s10 = hph10, s11 = hph11 + crm1;
    float idet = 1.0f/(s00*s11 - s01*s10);
    float i00 =  s11*idet, i01 = -s01*idet, i10 = -s10*idet, i11 = s00*idet;
    float K0 = i00*hpr0 + i01*hpr1;
    float K1 = i10*hpr0 + i11*hpr1;
    float s01q = 0.5f*(s01 + s10);
    float dxval = K0*rr0 + K1*rr1;

    float dx0 = RL(dxval,0), dx1 = RL(dxval,1), dx2 = RL(dxval,2);
    float dx3 = RL(dxval,3), dx4 = RL(dxval,4), dx5 = RL(dxval,5);
    float dx6 = RL(dxval,6), dx7 = RL(dxval,7), dx8 = RL(dxval,8);
    float dx15 = RL(dxval,15), dx16 = RL(dxval,16), dx17 = RL(dxval,17);
    int src = (l>=30 && l<33)? (l-12) : ((l>=15 && l<21)? (l-6) : 0);
    float dxadd = __shfl(dxval, src);

    // ---- dR, Jm, Ec (uniform; also covers W1) ----
    float t2x = dx0*dx0+dx1*dx1+dx2*dx2;
    float cX,k1X,k2X,j1X;
    if (t2x < 1e-4f){
      cX  = 1.f - t2x*(0.5f - t2x*((1.f/24.f) - t2x*(1.f/720.f)));
      k2X = 1.f - t2x*((1.f/6.f) - t2x*((1.f/120.f) - t2x*(1.f/5040.f)));
      k1X = 0.5f - t2x*((1.f/24.f) - t2x*(1.f/720.f));
      j1X = (1.f/6.f) - t2x*((1.f/120.f) - t2x*(1.f/5040.f));
    } else {
      float a = sqrtf(t2x);
      cX = __cosf(a);
      float s = __sinf(a);
      k2X = s/a; k1X = (1.f-cX)/t2x; j1X = (1.f-k2X)/t2x;
    }
    float dR[9];
    dR[0]=cX+k1X*dx0*dx0;      dR[1]=k1X*dx0*dx1-k2X*dx2; dR[2]=k1X*dx0*dx2+k2X*dx1;
    dR[3]=k1X*dx0*dx1+k2X*dx2; dR[4]=cX+k1X*dx1*dx1;      dR[5]=k1X*dx1*dx2-k2X*dx0;
    dR[6]=k1X*dx0*dx2-k2X*dx1; dR[7]=k1X*dx1*dx2+k2X*dx0; dR[8]=cX+k1X*dx2*dx2;
    float Jm[9];
    Jm[0]=k2X+j1X*dx0*dx0;      Jm[1]=j1X*dx0*dx1-k1X*dx2; Jm[2]=j1X*dx0*dx2+k1X*dx1;
    Jm[3]=j1X*dx0*dx1+k1X*dx2;  Jm[4]=k2X+j1X*dx1*dx1;     Jm[5]=j1X*dx1*dx2-k1X*dx0;
    Jm[6]=j1X*dx0*dx2-k1X*dx1;  Jm[7]=j1X*dx1*dx2+k1X*dx0; Jm[8]=k2X+j1X*dx2*dx2;
    float Ec[9];
    rot_from_t2(dx15*dx15+dx16*dx16+dx17*dx17, dx15,dx16,dx17, Ec);

    WAVE_SYNC();  // W1: PnS + HPs2 visible (drain covered by S/K/dR/Jm/Ec)

    // ===== stage Pu: P = Pn_sym - [K[r].HP[:,c] + K[c].HP[:,r]] + K[r] Ssym K[c] =====
    if (l<63){
      int r = c21;
#pragma unroll
      for (int s=0;s<7;++s){
        int j = (s<3)? (g21 + 3*s) : (cw + (s-3));
        float pnT = PnS[j*LDP + r];
        float2 hpj = HPs2[j];
        float kjx = i00*hpj.x + i01*hpj.y;
        float kjy = i10*hpj.x + i11*hpj.y;
        float base  = 0.5f*(pnv[s] + pnT);
        float cross = (K0*hpj.x + K1*hpj.y) + (kjx*hpr0 + kjy*hpr1);
        float quad  = (K0*kjx)*s00 + (K0*kjy + K1*kjx)*s01q + (K1*kjy)*s11;
        Pm[r*LDP+j] = base - cross + quad;
      }
    }

    // ===== per-lane state update (covers W2 drain) =====
    float myval = 0.f;
    if (l<9){
      int ro=(l>=6)?2:((l>=3)?1:0); int co=l-3*ro;
      float d0=sel3(ro,dR[0],dR[3],dR[6]), d1=sel3(ro,dR[1],dR[4],dR[7]), d2=sel3(ro,dR[2],dR[5],dR[8]);
      float n0=sel3(co,Rn[0],Rn[1],Rn[2]), n1=sel3(co,Rn[3],Rn[4],Rn[5]), n2=sel3(co,Rn[6],Rn[7],Rn[8]);
      myval = d0*n0 + d1*n1 + d2*n2;
    } else if (l<15){
      int j=l-9; bool isv=(j<3); int ro = isv? j : (j-3);
      float x0 = isv? vn0:pn0, x1 = isv? vn1:pn1, x2 = isv? vn2:pn2;
      float y0 = isv? dx3:dx6, y1 = isv? dx4:dx7, y2 = isv? dx5:dx8;
      float d0=sel3(ro,dR[0],dR[3],dR[6]), d1=sel3(ro,dR[1],dR[4],dR[7]), d2=sel3(ro,dR[2],dR[5],dR[8]);
      float j0=sel3(ro,Jm[0],Jm[3],Jm[6]), j1m=sel3(ro,Jm[1],Jm[4],Jm[7]), j2m=sel3(ro,Jm[2],Jm[5],Jm[8]);
      myval = d0*x0 + d1*x1 + d2*x2 + j0*y0 + j1m*y1 + j2m*y2;
    } else if (l<21){
      float old = (l<18)? sel3(l-15,bw0,bw1,bw2) : sel3(l-18,ba0,ba1,ba2);
      myval = old + dxadd;
    } else if (l<30){
      int j=l-21; int ro=(j>=6)?2:((j>=3)?1:0); int co=j-3*ro;
      float e0=sel3(ro,Ec[0],Ec[3],Ec[6]), e1=sel3(ro,Ec[1],Ec[4],Ec[7]), e2=sel3(ro,Ec[2],Ec[5],Ec[8]);
      float r0=sel3(co,Rc[0],Rc[1],Rc[2]), r1=sel3(co,Rc[3],Rc[4],Rc[5]), r2=sel3(co,Rc[6],Rc[7],Rc[8]);
      myval = e0*r0 + e1*r1 + e2*r2;
    } else if (l<33){
      myval = sel3(l-30,tc0,tc1,tc2) + dxadd;
    }
    if (l<33) stS[l] = myval;

    // ---- periodic renormalization (uniform branch) ----
    bool n100 = (i==nx100), n1000 = (i==nx1000);
    if (n100) nx100 += 100;
    if (n1000) nx1000 += 1000;
    if (n100 || n1000){
      WAVE_SYNC();   // stS writes visible wave-wide
      if (n100){
        float X[9];
#pragma unroll
        for (int k=0;k<9;++k) X[k]=stS[k];
        normalize_rot9(X);
        if (l<9){ myval = pick9(l,X); stS[l] = myval; }
      }
      if (n1000){
        float Y[9];
#pragma unroll
        for (int k=0;k<9;++k) Y[k]=stS[21+k];
        normalize_rot9(Y);
        if (l>=21 && l<30){ myval = pick9(l-21,Y); stS[l] = myval; }
      }
    }

    if (l<33) op[i*ostr] = myval;

    WAVE_SYNC();  // W2: Pm + stS visible for next iteration
  }
}

extern "C" void kernel_launch(void* const* d_in, const int* in_sizes, int n_in,
                              void* d_out, int out_size, void* d_ws, size_t ws_size,
                              hipStream_t stream) {
  (void)n_in; (void)out_size; (void)d_ws; (void)ws_size;
  const float* t     = (const float*)d_in[0];
  const float* u     = (const float*)d_in[1];
  const float* mcov  = (const float*)d_in[2];
  const float* v_mes = (const float*)d_in[3];
  const float* ang0  = (const float*)d_in[5];
  int N = in_sizes[0];
  iekf_scan_kernel<<<dim3(1), dim3(64), 0, stream>>>(t, u, mcov, v_mes, ang0, (float*)d_out, N);
}